// Round 9
// baseline (348.263 us; speedup 1.0000x reference)
//
#include <hip/hip_runtime.h>
#include <hip/hip_bf16.h>
#include <cstddef>

#define NA 200000   // atoms
#define EA 800000   // atom-graph edges
#define NF 20000    // fragments
#define EF 60000    // fragment-graph edges
// D = 128, hidden = 256
#define NSEG (NA + 2 * NF)          // concatenated count array length (240000)
#define TOTW (EA + NA + EF)         // fused hist/fill work items (1060000)
#define NC 8                        // XCD-private counter copies

typedef unsigned short ushort_t;
typedef __attribute__((ext_vector_type(8))) short bf16x8;
typedef __attribute__((ext_vector_type(4))) float f32x4;

__device__ __forceinline__ unsigned short f2bf(float f) {
  unsigned u = __builtin_bit_cast(unsigned, f);
  u += 0x7FFFu + ((u >> 16) & 1u);  // round-to-nearest-even
  return (unsigned short)(u >> 16);
}
__device__ __forceinline__ float bf2f(unsigned short h) {
  unsigned u = ((unsigned)h) << 16;
  return __builtin_bit_cast(float, u);
}

// ================= fused histogram — fp32 unsafeAtomicAdd ===================
// Int atomicAdd takes the system-coherent (write-through) path: measured
// 26 G/s, WRITE_SIZE = 32 B/atomic (R8). Float unsafeAtomicAdd measured at
// 76 G/s in R1 on this problem with correct results. Counts << 2^24 -> exact.
__global__ __launch_bounds__(256) void k_hist_all(
    const int* __restrict__ ei, const int* __restrict__ a2f,
    const int* __restrict__ fi, float* __restrict__ src8,
    float* __restrict__ cnt8) {
  int idx = blockIdx.x * 256 + threadIdx.x;
  const int c = blockIdx.x & (NC - 1);
  if (idx < EA) {
    unsafeAtomicAdd(&src8[c * NA + ei[idx]], 1.0f);
    unsafeAtomicAdd(&cnt8[c * NSEG + ei[EA + idx]], 1.0f);
  } else if (idx < EA + NA) {
    unsafeAtomicAdd(&cnt8[c * NSEG + NA + a2f[idx - EA]], 1.0f);
  } else if (idx < TOTW) {
    unsafeAtomicAdd(&cnt8[c * NSEG + NA + NF + fi[EF + (idx - EA - NA)]], 1.0f);
  }
}

// ============ reduce 8 copies: totals + per-copy prefix + dinv ==============
__global__ __launch_bounds__(256) void k_reduce8(
    float* __restrict__ cnt8, const float* __restrict__ src8,
    int* __restrict__ cnt_all, float* __restrict__ dinv) {
  int i = blockIdx.x * 256 + threadIdx.x;
  if (i < NSEG) {
    int s = 0;
#pragma unroll
    for (int c = 0; c < NC; ++c) {
      int t = (int)cnt8[c * NSEG + i];
      cnt8[c * NSEG + i] = (float)s;  // exclusive prefix over copies
      s += t;
    }
    cnt_all[i] = s;
  }
  if (i < NA) {
    int d = 0;
#pragma unroll
    for (int c = 0; c < NC; ++c) d += (int)src8[c * NA + i];
    dinv[i] = rsqrtf((float)(1 + d));
  }
}

// ================= exclusive scan over cnt_all ==============================
__global__ __launch_bounds__(256) void k_scan1(const int* __restrict__ cnt,
                                               int* __restrict__ rp,
                                               int* __restrict__ bsum, int n) {
  __shared__ int sh[256];
  const int base = blockIdx.x * 1024;
  const int tid = threadIdx.x;
  int v[4], s = 0;
#pragma unroll
  for (int j = 0; j < 4; ++j) {
    int idx = base + tid * 4 + j;
    v[j] = (idx < n) ? cnt[idx] : 0;
    s += v[j];
  }
  sh[tid] = s;
  __syncthreads();
  for (int off = 1; off < 256; off <<= 1) {
    int t = (tid >= off) ? sh[tid - off] : 0;
    __syncthreads();
    sh[tid] += t;
    __syncthreads();
  }
  int excl = (tid > 0) ? sh[tid - 1] : 0;
#pragma unroll
  for (int j = 0; j < 4; ++j) {
    int idx = base + tid * 4 + j;
    if (idx < n) rp[idx] = excl;
    excl += v[j];
  }
  if (tid == 255) bsum[blockIdx.x] = sh[255];
}
__global__ __launch_bounds__(1024) void k_scan2(int* __restrict__ bsum, int nb) {
  __shared__ int sh[1024];
  const int tid = threadIdx.x;
  sh[tid] = (tid < nb) ? bsum[tid] : 0;
  __syncthreads();
  for (int off = 1; off < 1024; off <<= 1) {
    int t = (tid >= off) ? sh[tid - off] : 0;
    __syncthreads();
    sh[tid] += t;
    __syncthreads();
  }
  if (tid < nb) bsum[tid] = (tid > 0) ? sh[tid - 1] : 0;  // exclusive
}
__global__ __launch_bounds__(256) void k_scan3(int* __restrict__ rp,
                                               const int* __restrict__ bsum,
                                               int n) {
  int i = blockIdx.x * 256 + threadIdx.x;
  if (i < n) rp[i] += bsum[i >> 10];
}

// ================= fused CSR fill — fp32 cursor atomics =====================
// Same idx->block->copy mapping as k_hist_all, so per-(copy,seg) counts agree.
__global__ __launch_bounds__(256) void k_fill_all(
    const int* __restrict__ ei, const int* __restrict__ a2f,
    const int* __restrict__ fi, const int* __restrict__ rp,
    const float* __restrict__ pfx8, float* __restrict__ cur8,
    int* __restrict__ lst) {
  int idx = blockIdx.x * 256 + threadIdx.x;
  const int c = blockIdx.x & (NC - 1);
  if (idx < EA) {
    int t = ei[EA + idx];
    int p = (int)unsafeAtomicAdd(&cur8[c * NSEG + t], 1.0f);
    lst[rp[t] + (int)pfx8[c * NSEG + t] + p] = ei[idx];      // src atom
  } else if (idx < EA + NA) {
    int i = idx - EA;
    int t = NA + a2f[i];
    int p = (int)unsafeAtomicAdd(&cur8[c * NSEG + t], 1.0f);
    lst[rp[t] + (int)pfx8[c * NSEG + t] + p] = i;            // atom id
  } else if (idx < TOTW) {
    int e = idx - EA - NA;
    int t = NA + NF + fi[EF + e];
    int p = (int)unsafeAtomicAdd(&cur8[c * NSEG + t], 1.0f);
    lst[rp[t] + (int)pfx8[c * NSEG + t] + p] = fi[e];        // fs
  }
}

// ======== Wt[c][k] = bf16(W[k][c]) — tiny precompute ========================
__global__ __launch_bounds__(256) void k_wt(const float* __restrict__ W,
                                            ushort_t* __restrict__ Wt) {
  int idx = blockIdx.x * 256 + threadIdx.x;  // 16384
  if (idx < 128 * 128) {
    int c = idx >> 7, k = idx & 127;
    Wt[idx] = f2bf(W[k * 128 + c]);
  }
}

// ======== y = bf16( (x_atoms @ W_atom + b_atom) * dinv[row] ) — MFMA ========
__global__ __launch_bounds__(256) void k_gemm_y(
    const float* __restrict__ xa, const ushort_t* __restrict__ Wt,
    const float* __restrict__ b, const float* __restrict__ dinv,
    ushort_t* __restrict__ y) {
  __shared__ ushort_t Asl[64 * 128];   // 16 KB, swizzled bf16 A
  __shared__ ushort_t Bsl[128 * 128];  // 32 KB, swizzled bf16 Wt
  const int tid = threadIdx.x;
  const int brow = blockIdx.x * 64;
  {  // stage A: cvt to bf16, swizzled ds_write (8 B units)
    const float4* gA = reinterpret_cast<const float4*>(xa + (size_t)brow * 128);
#pragma unroll
    for (int i = 0; i < 8; ++i) {
      int f = tid + i * 256;
      int row = f >> 5;
      int kq = f & 31;
      float4 v = gA[f];
      ushort4 u;
      u.x = f2bf(v.x); u.y = f2bf(v.y); u.z = f2bf(v.z); u.w = f2bf(v.w);
      int koff = (kq * 4) ^ ((row & 7) << 3);
      *reinterpret_cast<ushort4*>(&Asl[row * 128 + koff]) = u;
    }
    const uint4* gW = reinterpret_cast<const uint4*>(Wt);
#pragma unroll
    for (int i = 0; i < 8; ++i) {
      int u = tid + i * 256;
      int c = u >> 4;
      int k8 = u & 15;
      uint4 v = gW[u];
      int koff = (k8 * 8) ^ ((c & 7) << 3);
      *reinterpret_cast<uint4*>(&Bsl[c * 128 + koff]) = v;
    }
  }
  __syncthreads();
  const int w = tid >> 6;
  const int l = tid & 63;
  const int lr = l & 15;
  const int g = l >> 4;
  const int r0 = w * 16;
  f32x4 acc[8] = {};
  const int arow = r0 + lr;
  const int asw = (arow & 7) << 3;
#pragma unroll
  for (int s = 0; s < 4; ++s) {
    const int kb = s * 32 + g * 4;
    ushort4 alo = *reinterpret_cast<const ushort4*>(&Asl[arow * 128 + (kb ^ asw)]);
    ushort4 ahi = *reinterpret_cast<const ushort4*>(&Asl[arow * 128 + ((kb + 16) ^ asw)]);
    bf16x8 a;
    a[0] = (short)alo.x; a[1] = (short)alo.y; a[2] = (short)alo.z; a[3] = (short)alo.w;
    a[4] = (short)ahi.x; a[5] = (short)ahi.y; a[6] = (short)ahi.z; a[7] = (short)ahi.w;
#pragma unroll
    for (int t = 0; t < 8; ++t) {
      const int bc = t * 16 + lr;
      const int bsw = (bc & 7) << 3;
      ushort4 blo = *reinterpret_cast<const ushort4*>(&Bsl[bc * 128 + (kb ^ bsw)]);
      ushort4 bhi = *reinterpret_cast<const ushort4*>(&Bsl[bc * 128 + ((kb + 16) ^ bsw)]);
      bf16x8 bf;
      bf[0] = (short)blo.x; bf[1] = (short)blo.y; bf[2] = (short)blo.z; bf[3] = (short)blo.w;
      bf[4] = (short)bhi.x; bf[5] = (short)bhi.y; bf[6] = (short)bhi.z; bf[7] = (short)bhi.w;
      acc[t] = __builtin_amdgcn_mfma_f32_16x16x32_bf16(a, bf, acc[t], 0, 0, 0);
    }
  }
  float di[4];
#pragma unroll
  for (int r = 0; r < 4; ++r) di[r] = dinv[brow + r0 + g * 4 + r];
#pragma unroll
  for (int t = 0; t < 8; ++t) {
    const int col = t * 16 + lr;
    const float bb = b[col];
#pragma unroll
    for (int r = 0; r < 4; ++r) {
      const int row = brow + r0 + g * 4 + r;
      y[(size_t)row * 128 + col] = f2bf((acc[t][r] + bb) * di[r]);
    }
  }
}

// ======== x_new[t] = dinv[t] * (y[t] + sum_{s->t} y[s])  (CSR gather) =======
__global__ __launch_bounds__(256) void k_gather_x(
    const int* __restrict__ rp, const int* __restrict__ cnt,
    const int* __restrict__ lst, const ushort_t* __restrict__ y,
    const float* __restrict__ dinv, float* __restrict__ xnew) {
  const int row = blockIdx.x * 8 + (threadIdx.x >> 5);
  const int c = (threadIdx.x & 31) << 2;
  const ushort4 vs = *reinterpret_cast<const ushort4*>(y + (size_t)row * 128 + c);
  f32x4 acc = {bf2f(vs.x), bf2f(vs.y), bf2f(vs.z), bf2f(vs.w)};
  const int start = rp[row];
  const int deg = cnt[row];
  int j = 0;
  for (; j + 4 <= deg; j += 4) {
    const int s0 = lst[start + j + 0];
    const int s1 = lst[start + j + 1];
    const int s2 = lst[start + j + 2];
    const int s3 = lst[start + j + 3];
    const ushort4 v0 = *reinterpret_cast<const ushort4*>(y + (size_t)s0 * 128 + c);
    const ushort4 v1 = *reinterpret_cast<const ushort4*>(y + (size_t)s1 * 128 + c);
    const ushort4 v2 = *reinterpret_cast<const ushort4*>(y + (size_t)s2 * 128 + c);
    const ushort4 v3 = *reinterpret_cast<const ushort4*>(y + (size_t)s3 * 128 + c);
    acc.x += bf2f(v0.x) + bf2f(v1.x) + bf2f(v2.x) + bf2f(v3.x);
    acc.y += bf2f(v0.y) + bf2f(v1.y) + bf2f(v2.y) + bf2f(v3.y);
    acc.z += bf2f(v0.z) + bf2f(v1.z) + bf2f(v2.z) + bf2f(v3.z);
    acc.w += bf2f(v0.w) + bf2f(v1.w) + bf2f(v2.w) + bf2f(v3.w);
  }
  for (; j < deg; ++j) {
    const int s = lst[start + j];
    const ushort4 v = *reinterpret_cast<const ushort4*>(y + (size_t)s * 128 + c);
    acc.x += bf2f(v.x); acc.y += bf2f(v.y); acc.z += bf2f(v.z); acc.w += bf2f(v.w);
  }
  const float dt = dinv[row];
  acc.x *= dt; acc.y *= dt; acc.z *= dt; acc.w *= dt;
  __builtin_nontemporal_store(acc, reinterpret_cast<f32x4*>(xnew + (size_t)row * 128 + c));
}

// ======== ff[f] = sum_{atoms i in f} xnew[i]  (CSR gather) ==================
__global__ __launch_bounds__(256) void k_gather_ff(
    const int* __restrict__ rp, const int* __restrict__ cnt,
    const int* __restrict__ lst, const float* __restrict__ xnew,
    float* __restrict__ ff) {
  const int f = blockIdx.x * 8 + (threadIdx.x >> 5);
  const int c = (threadIdx.x & 31) << 2;
  float4 acc = {0.f, 0.f, 0.f, 0.f};
  const int start = rp[f];
  const int deg = cnt[f];
  int j = 0;
  for (; j + 4 <= deg; j += 4) {
    const int s0 = lst[start + j + 0];
    const int s1 = lst[start + j + 1];
    const int s2 = lst[start + j + 2];
    const int s3 = lst[start + j + 3];
    const float4 v0 = *reinterpret_cast<const float4*>(xnew + (size_t)s0 * 128 + c);
    const float4 v1 = *reinterpret_cast<const float4*>(xnew + (size_t)s1 * 128 + c);
    const float4 v2 = *reinterpret_cast<const float4*>(xnew + (size_t)s2 * 128 + c);
    const float4 v3 = *reinterpret_cast<const float4*>(xnew + (size_t)s3 * 128 + c);
    acc.x += v0.x + v1.x + v2.x + v3.x;
    acc.y += v0.y + v1.y + v2.y + v3.y;
    acc.z += v0.z + v1.z + v2.z + v3.z;
    acc.w += v0.w + v1.w + v2.w + v3.w;
  }
  for (; j < deg; ++j) {
    const int s = lst[start + j];
    const float4 v = *reinterpret_cast<const float4*>(xnew + (size_t)s * 128 + c);
    acc.x += v.x; acc.y += v.y; acc.z += v.z; acc.w += v.w;
  }
  *reinterpret_cast<float4*>(ff + (size_t)f * 128 + c) = acc;
}

// ======== fused: fsum gather (frag edges) + 2-layer MLP =====================
__global__ __launch_bounds__(256) void k_mlp(
    const int* __restrict__ rp, const int* __restrict__ cnt,
    const int* __restrict__ lst, const float* __restrict__ ff,
    const float* __restrict__ W1, const float* __restrict__ b1,
    const float* __restrict__ W2, const float* __restrict__ b2,
    float* __restrict__ out) {
  __shared__ float As[32][128];
  __shared__ float hs[32][256];
  const int row0 = blockIdx.x * 32;
  {  // gather: 8 groups x 32 lanes; each group handles 4 rows
    const int g = threadIdx.x >> 5;
    const int c = (threadIdx.x & 31) << 2;
#pragma unroll
    for (int rr = 0; rr < 4; ++rr) {
      const int f = row0 + g * 4 + rr;
      const int start = rp[f];
      const int deg = cnt[f];
      float4 acc = {0.f, 0.f, 0.f, 0.f};
      for (int j = 0; j < deg; ++j) {
        const int s = lst[start + j];
        const float4 v = *reinterpret_cast<const float4*>(ff + (size_t)s * 128 + c);
        acc.x += v.x; acc.y += v.y; acc.z += v.z; acc.w += v.w;
      }
      *reinterpret_cast<float4*>(&As[g * 4 + rr][c]) = acc;
    }
  }
  __syncthreads();
  {  // GEMM1
    const int tc = threadIdx.x & 63;
    const int tr = threadIdx.x >> 6;
    const int c0 = tc * 4;
    float acc[8][4] = {};
    for (int k0 = 0; k0 < 128; k0 += 4) {
      float4 w0 = *reinterpret_cast<const float4*>(&W1[(k0 + 0) * 256 + c0]);
      float4 w1 = *reinterpret_cast<const float4*>(&W1[(k0 + 1) * 256 + c0]);
      float4 w2 = *reinterpret_cast<const float4*>(&W1[(k0 + 2) * 256 + c0]);
      float4 w3 = *reinterpret_cast<const float4*>(&W1[(k0 + 3) * 256 + c0]);
#pragma unroll
      for (int r = 0; r < 8; ++r) {
        float4 a = *reinterpret_cast<const float4*>(&As[tr * 8 + r][k0]);
        acc[r][0] += a.x * w0.x + a.y * w1.x + a.z * w2.x + a.w * w3.x;
        acc[r][1] += a.x * w0.y + a.y * w1.y + a.z * w2.y + a.w * w3.y;
        acc[r][2] += a.x * w0.z + a.y * w1.z + a.z * w2.z + a.w * w3.z;
        acc[r][3] += a.x * w0.w + a.y * w1.w + a.z * w2.w + a.w * w3.w;
      }
    }
    const float4 bc = *reinterpret_cast<const float4*>(&b1[c0]);
#pragma unroll
    for (int r = 0; r < 8; ++r) {
      float4 h;
      h.x = fmaxf(acc[r][0] + bc.x, 0.f);
      h.y = fmaxf(acc[r][1] + bc.y, 0.f);
      h.z = fmaxf(acc[r][2] + bc.z, 0.f);
      h.w = fmaxf(acc[r][3] + bc.w, 0.f);
      *reinterpret_cast<float4*>(&hs[tr * 8 + r][c0]) = h;
    }
  }
  __syncthreads();
  {  // GEMM2
    const int tc = threadIdx.x & 31;
    const int tr = threadIdx.x >> 5;
    const int c0 = tc * 4;
    float acc[4][4] = {};
    for (int k0 = 0; k0 < 256; k0 += 4) {
      float4 w0 = *reinterpret_cast<const float4*>(&W2[(k0 + 0) * 128 + c0]);
      float4 w1 = *reinterpret_cast<const float4*>(&W2[(k0 + 1) * 128 + c0]);
      float4 w2 = *reinterpret_cast<const float4*>(&W2[(k0 + 2) * 128 + c0]);
      float4 w3 = *reinterpret_cast<const float4*>(&W2[(k0 + 3) * 128 + c0]);
#pragma unroll
      for (int r = 0; r < 4; ++r) {
        float4 a = *reinterpret_cast<const float4*>(&hs[tr * 4 + r][k0]);
        acc[r][0] += a.x * w0.x + a.y * w1.x + a.z * w2.x + a.w * w3.x;
        acc[r][1] += a.x * w0.y + a.y * w1.y + a.z * w2.y + a.w * w3.y;
        acc[r][2] += a.x * w0.z + a.y * w1.z + a.z * w2.z + a.w * w3.z;
        acc[r][3] += a.x * w0.w + a.y * w1.w + a.z * w2.w + a.w * w3.w;
      }
    }
    const float4 bc = *reinterpret_cast<const float4*>(&b2[c0]);
#pragma unroll
    for (int r = 0; r < 4; ++r) {
      float4 o;
      o.x = acc[r][0] + bc.x;
      o.y = acc[r][1] + bc.y;
      o.z = acc[r][2] + bc.z;
      o.w = acc[r][3] + bc.w;
      *reinterpret_cast<float4*>(&out[(size_t)(row0 + tr * 4 + r) * 128 + c0]) = o;
    }
  }
}

extern "C" void kernel_launch(void* const* d_in, const int* in_sizes, int n_in,
                              void* d_out, int out_size, void* d_ws, size_t ws_size,
                              hipStream_t stream) {
  // Bond-graph GAT inputs are dead code w.r.t. the returned outputs.
  const float* x_atoms    = (const float*)d_in[0];
  const int*   edge_index = (const int*)d_in[1];
  const int*   frag_index = (const int*)d_in[3];
  const int*   a2f        = (const int*)d_in[5];
  const float* W_atom     = (const float*)d_in[9];
  const float* b_atom     = (const float*)d_in[10];
  const float* W_f1       = (const float*)d_in[16];
  const float* b_f1       = (const float*)d_in[17];
  const float* W_f2       = (const float*)d_in[18];
  const float* b_f2       = (const float*)d_in[19];

  char* ws = (char*)d_ws;
  size_t off = 0;
  auto alloc = [&](size_t bytes) {
    void* p = ws + off;
    off += (bytes + 255) & ~(size_t)255;
    return p;
  };
  // --- zeroed-each-call pool (fp32 counters/cursors) ---
  float* src8 = (float*)alloc((size_t)NC * NA * 4);     // 6.4 MB
  float* cnt8 = (float*)alloc((size_t)NC * NSEG * 4);   // 7.7 MB (-> per-copy prefix)
  float* cur8 = (float*)alloc((size_t)NC * NSEG * 4);   // 7.7 MB
  const size_t zero_bytes = off;
  // --- rebuilt-each-call ---
  int* cnt_all = (int*)alloc((size_t)NSEG * 4);
  int* rp_all  = (int*)alloc(((size_t)NSEG + 1) * 4);
  int* bsum    = (int*)alloc(1024 * 4);
  int* lst     = (int*)alloc((size_t)TOTW * 4);
  float* dinv  = (float*)alloc((size_t)NA * 4);
  ushort_t* Wt = (ushort_t*)alloc((size_t)128 * 128 * 2);  // bf16 W^T
  ushort_t* y  = (ushort_t*)alloc((size_t)NA * 128 * 2);   // bf16
  float* ff    = (float*)alloc((size_t)NF * 128 * 4);

  float* xnew = (float*)d_out;                     // [NA,128]
  float* fout = (float*)d_out + (size_t)NA * 128;  // [NF,128]

  (void)hipMemsetAsync(ws, 0, zero_bytes, stream);

  k_hist_all<<<(TOTW + 255) / 256, 256, 0, stream>>>(edge_index, a2f, frag_index,
                                                     src8, cnt8);
  k_wt<<<64, 256, 0, stream>>>(W_atom, Wt);
  k_reduce8<<<(NSEG + 255) / 256, 256, 0, stream>>>(cnt8, src8, cnt_all, dinv);
  {
    int nb = (NSEG + 1023) / 1024;  // 235
    k_scan1<<<nb, 256, 0, stream>>>(cnt_all, rp_all, bsum, NSEG);
    k_scan2<<<1, 1024, 0, stream>>>(bsum, nb);
    k_scan3<<<(NSEG + 255) / 256, 256, 0, stream>>>(rp_all, bsum, NSEG);
  }
  k_fill_all<<<(TOTW + 255) / 256, 256, 0, stream>>>(edge_index, a2f, frag_index,
                                                     rp_all, cnt8, cur8, lst);

  k_gemm_y  <<<NA / 64, 256, 0, stream>>>(x_atoms, Wt, b_atom, dinv, y);
  k_gather_x<<<NA / 8, 256, 0, stream>>>(rp_all, cnt_all, lst, y, dinv, xnew);
  k_gather_ff<<<NF / 8, 256, 0, stream>>>(rp_all + NA, cnt_all + NA, lst, xnew, ff);
  k_mlp     <<<NF / 32, 256, 0, stream>>>(rp_all + NA + NF, cnt_all + NA + NF, lst,
                                          ff, W_f1, b_f1, W_f2, b_f2, fout);
}